// Round 3
// baseline (744.633 us; speedup 1.0000x reference)
//
#include <hip/hip_runtime.h>
#include <hip/hip_cooperative_groups.h>

namespace cg = cooperative_groups;

// Problem constants (from reference file)
#define N0_SRC 200000
#define N1_DST 50000
#define N2_DST 12000
#define N3_DST 3000
#define NTOT_DST 65000   // N1+N2+N3 (multiple of 4)
#define DH 256           // D_IN == D_H == 256
#define DOUT 64
#define EMAX_TOT 650000  // E0+E1+E2

typedef __attribute__((ext_vector_type(8))) short short8;
typedef __attribute__((ext_vector_type(4))) float f32x4;

__device__ __forceinline__ ushort f2bf(float f) {
    union { float f; uint32_t u; } v; v.f = f;
    uint32_t r = (v.u + 0x7FFF + ((v.u >> 16) & 1)) >> 16;  // RNE
    return (ushort)r;
}
__device__ __forceinline__ float bf2f(ushort u) {
    union { uint32_t u; float f; } v; v.u = ((uint32_t)u) << 16;
    return v.f;
}

// global -> LDS direct copy, 16B per lane. LDS dest is wave-uniform base +
// lane*16 (m104); caller passes the wave-uniform LDS base pointer.
__device__ __forceinline__ void gload16(const ushort* g, ushort* l) {
    __builtin_amdgcn_global_load_lds(
        (const __attribute__((address_space(1))) unsigned int*)g,
        (__attribute__((address_space(3))) unsigned int*)l,
        16, 0, 0);
}

// ---------------------------------------------------------------------------
// Cooperative prep + CSR mega-kernel (replaces 5 dispatches):
// phase 0: zero cnt, convert x[:N1] to bf16, transpose 6 weights
// phase 1: histogram (atomicAdd)
// phase 2: 2-level exclusive scan -> off, cursor
// phase 3: fill eidx via cursor atomics
// Grid: 256 blocks x 256 threads (co-resident: 1 block/CU).
// ---------------------------------------------------------------------------
struct PrepArgs {
    const float* x;
    const float* W[6];
    const int* s0; const int* d0; int E0;
    const int* s1; const int* d1; int E1;
    const int* s2; const int* d2; int E2;
    ushort* Wt; ushort* xb50;
    int* cnt; int* off; int* cursor; int* eidx; int* partial;
};

__global__ __launch_bounds__(256) void prep_csr_kernel(PrepArgs a) {
    cg::grid_group grid = cg::this_grid();
    __shared__ int red[4];
    __shared__ int tsum[256];
    __shared__ int pbase;
    const int GT = 256 * 256;
    int gt = blockIdx.x * 256 + threadIdx.x;
    int t  = threadIdx.x;

    // --- Phase 0a: zero cnt ---
    for (int i = gt; i < NTOT_DST; i += GT) a.cnt[i] = 0;
    // --- Phase 0b: convert x[:N1] fp32 -> bf16 (float4 strided) ---
    {
        const float4* xv = (const float4*)a.x;
        ushort4* xo = (ushort4*)a.xb50;
        const int nv = N1_DST * DH / 4;
        for (int i = gt; i < nv; i += GT) {
            float4 v = xv[i];
            ushort4 o;
            o.x = f2bf(v.x); o.y = f2bf(v.y); o.z = f2bf(v.z); o.w = f2bf(v.w);
            xo[i] = o;
        }
    }
    // --- Phase 0c: six weight transposes W[K][N] -> Wt[N][K] bf16 ---
    for (int i = gt; i < 294912; i += GT) {
        const float* W; ushort* o; int id; int Ndim;
        if (i < 262144) { int wy = i >> 16; id = i & 65535; W = a.W[wy]; o = a.Wt + (wy << 16); Ndim = 256; }
        else { int j = i - 262144; int wy = j >> 14; id = j & 16383; W = a.W[4 + wy]; o = a.Wt + 262144 + (wy << 14); Ndim = 64; }
        int n = id >> 8, k = id & 255;
        o[id] = f2bf(W[k * Ndim + n]);
    }
    grid.sync();

    // --- Phase 1: histogram ---
    for (int e = gt; e < a.E0; e += GT) atomicAdd(&a.cnt[a.d0[e]], 1);
    for (int e = gt; e < a.E1; e += GT) atomicAdd(&a.cnt[N1_DST + a.d1[e]], 1);
    for (int e = gt; e < a.E2; e += GT) atomicAdd(&a.cnt[N1_DST + N2_DST + a.d2[e]], 1);
    grid.sync();

    // --- Phase 2a: per-block sums over 1024-int chunks (blocks 0..63) ---
    if (blockIdx.x < 64) {
        int i = blockIdx.x * 1024 + t * 4;
        int s = 0;
        if (i + 3 < NTOT_DST) {
            int4 v = *(const int4*)(a.cnt + i);
            s = v.x + v.y + v.z + v.w;
        }
#pragma unroll
        for (int d = 32; d; d >>= 1) s += __shfl_down(s, d, 64);
        if ((t & 63) == 0) red[t >> 6] = s;
        __syncthreads();
        if (t == 0) a.partial[blockIdx.x] = red[0] + red[1] + red[2] + red[3];
    }
    grid.sync();

    // --- Phase 2b: every block re-scans the 64 partials, then its chunk ---
    if (blockIdx.x < 64) {
        if (t < 64) {
            int own = a.partial[t];
            int v = own;
#pragma unroll
            for (int d = 1; d < 64; d <<= 1) {
                int u = __shfl_up(v, d, 64);
                if (t >= d) v += u;
            }
            if (t == (int)blockIdx.x) pbase = v - own;  // exclusive prefix
        }
        int i = blockIdx.x * 1024 + t * 4;
        int4 c = make_int4(0, 0, 0, 0);
        if (i + 3 < NTOT_DST) c = *(const int4*)(a.cnt + i);
        int s = c.x + c.y + c.z + c.w;
        tsum[t] = s;
        __syncthreads();
#pragma unroll
        for (int d = 1; d < 256; d <<= 1) {
            int u = (t >= d) ? tsum[t - d] : 0;
            __syncthreads();
            tsum[t] += u;
            __syncthreads();
        }
        int base = pbase + tsum[t] - s;
        if (i + 3 < NTOT_DST) {
            int4 ov;
            ov.x = base;
            ov.y = ov.x + c.x;
            ov.z = ov.y + c.y;
            ov.w = ov.z + c.z;
            *(int4*)(a.off + i) = ov;
            *(int4*)(a.cursor + i) = ov;
            if (i + 4 == NTOT_DST) a.off[NTOT_DST] = ov.w + c.w;
        }
    }
    grid.sync();

    // --- Phase 3: fill eidx ---
    for (int e = gt; e < a.E0; e += GT) { int p = atomicAdd(&a.cursor[a.d0[e]], 1); a.eidx[p] = a.s0[e]; }
    for (int e = gt; e < a.E1; e += GT) { int p = atomicAdd(&a.cursor[N1_DST + a.d1[e]], 1); a.eidx[p] = a.s1[e]; }
    for (int e = gt; e < a.E2; e += GT) { int p = atomicAdd(&a.cursor[N1_DST + N2_DST + a.d2[e]], 1); a.eidx[p] = a.s2[e]; }
}

// ---------------------------------------------------------------------------
// Fused gather-mean + dual MFMA GEMM per layer.
// Block = 64 output rows (BM=64), 4 waves. Phase 1: each wave gather-means
// 16 dst rows into padded LDS tile AnS[64][264] (bf16; pad -> conflict-free
// MFMA reads: 8 lanes per 4-bank group). Phase 2: K-loop; self-A rows and
// both weight tiles staged per k-step via global_load_lds into linear LDS
// with the both-sides XOR segment swizzle (rule 21). Wave-tiling MT=4,NT=NT:
// wave w owns cols [w*NT*16, (w+1)*NT*16) of all 64 rows -> 16 ds_read_b128
// feed 32 MFMA per k-step (2:1 MFMA:read, m97-class ratio).
// M-tail: staged/gathered rows clamped/zeroed; epilogue skips row >= M.
// ---------------------------------------------------------------------------
template <int NT, bool SRCF32, bool RELU, bool OUTBF>
__global__ __launch_bounds__(256) void fused_layer(
    const void* __restrict__ Hg,      // gather source (f32 x or bf16 h)
    const ushort* __restrict__ As,    // self rows, bf16
    const int* __restrict__ off, const int* __restrict__ eidx,
    const ushort* __restrict__ Wst, const ushort* __restrict__ Wnt,
    const float* __restrict__ bias, void* __restrict__ Cv,
    int M, int N) {
    const int K = 256;
    const int BN = NT * 64;   // 4 waves * NT*16 cols
    const int LDA = 264;      // padded neighbor-tile stride (shorts)
    __shared__ __align__(16) ushort AnS[64 * LDA];
    __shared__ __align__(16) ushort AsS[64 * 32];
    __shared__ __align__(16) ushort BsS[2 * BN * 32];
    ushort* Bss = BsS;
    ushort* Bsn = BsS + BN * 32;

    int tid = threadIdx.x, lane = tid & 63, wid = tid >> 6;
    int q = lane >> 4, mr = lane & 15;
    int row0 = blockIdx.x * 64;

    // ---- Gather phase: wave wid computes rows wid*16 .. wid*16+15 ----
    for (int rr = 0; rr < 16; ++rr) {
        int rho = wid * 16 + rr;
        int w = row0 + rho;
        float a0 = 0.f, a1 = 0.f, a2 = 0.f, a3 = 0.f;
        int deg = 0;
        if (w < M) {
            int beg = off[w], end = off[w + 1];
            deg = end - beg;
            for (int i = beg; i < end; i += 4) {
                int rem = end - i;  // >= 1
                int j1 = i + (rem > 1 ? 1 : 0);
                int j2 = i + (rem > 2 ? 2 : 0);
                int j3 = i + (rem > 3 ? 3 : 0);
                float m1 = rem > 1 ? 1.f : 0.f;
                float m2 = rem > 2 ? 1.f : 0.f;
                float m3 = rem > 3 ? 1.f : 0.f;
                int s0 = eidx[i], s1 = eidx[j1], s2 = eidx[j2], s3 = eidx[j3];
                if (SRCF32) {
                    const float4* h = (const float4*)Hg;
                    float4 v0 = h[(size_t)s0 * 64 + lane];
                    float4 v1 = h[(size_t)s1 * 64 + lane];
                    float4 v2 = h[(size_t)s2 * 64 + lane];
                    float4 v3 = h[(size_t)s3 * 64 + lane];
                    a0 += v0.x + m1 * v1.x + m2 * v2.x + m3 * v3.x;
                    a1 += v0.y + m1 * v1.y + m2 * v2.y + m3 * v3.y;
                    a2 += v0.z + m1 * v1.z + m2 * v2.z + m3 * v3.z;
                    a3 += v0.w + m1 * v1.w + m2 * v2.w + m3 * v3.w;
                } else {
                    const ushort4* h = (const ushort4*)Hg;
                    ushort4 v0 = h[(size_t)s0 * 64 + lane];
                    ushort4 v1 = h[(size_t)s1 * 64 + lane];
                    ushort4 v2 = h[(size_t)s2 * 64 + lane];
                    ushort4 v3 = h[(size_t)s3 * 64 + lane];
                    a0 += bf2f(v0.x) + m1 * bf2f(v1.x) + m2 * bf2f(v2.x) + m3 * bf2f(v3.x);
                    a1 += bf2f(v0.y) + m1 * bf2f(v1.y) + m2 * bf2f(v2.y) + m3 * bf2f(v3.y);
                    a2 += bf2f(v0.z) + m1 * bf2f(v1.z) + m2 * bf2f(v2.z) + m3 * bf2f(v3.z);
                    a3 += bf2f(v0.w) + m1 * bf2f(v1.w) + m2 * bf2f(v2.w) + m3 * bf2f(v3.w);
                }
            }
        }
        float inv = 1.0f / fmaxf((float)deg, 1.0f);
        ushort4 o;
        o.x = f2bf(a0 * inv); o.y = f2bf(a1 * inv);
        o.z = f2bf(a2 * inv); o.w = f2bf(a3 * inv);
        *(ushort4*)(&AnS[rho * LDA + lane * 4]) = o;
    }
    __syncthreads();

    // ---- Dual GEMM phase ----
    f32x4 acc[4][NT];
#pragma unroll
    for (int i = 0; i < 4; ++i)
#pragma unroll
        for (int j = 0; j < NT; ++j) acc[i][j] = (f32x4){0.f, 0.f, 0.f, 0.f};

    for (int k0 = 0; k0 < K; k0 += 32) {
        // Stage self-A tile (64 x 32): 256 chunks, 1 per thread.
        {
            int r = tid >> 2;
            int sg = (tid & 3) ^ ((r >> 1) & 3);
            int row = row0 + r;
            if (row > M - 1) row = M - 1;
            gload16(As + (size_t)row * K + k0 + sg * 8, AsS + (tid & ~63) * 8);
        }
        // Stage B tiles (BN x 32), both matrices.
#pragma unroll
        for (int c = 0; c < NT; ++c) {
            int chunk = c * 256 + tid;
            int r = chunk >> 2;
            int sg = (chunk & 3) ^ ((r >> 1) & 3);
            gload16(Wst + (size_t)r * K + k0 + sg * 8, Bss + (c * 256 + (tid & ~63)) * 8);
            gload16(Wnt + (size_t)r * K + k0 + sg * 8, Bsn + (c * 256 + (tid & ~63)) * 8);
        }
        __syncthreads();  // drains vmcnt(0) before barrier

        short8 av[4], aw[4];
#pragma unroll
        for (int mt = 0; mt < 4; ++mt) {
            int rho = mt * 16 + mr;
            av[mt] = *(const short8*)(AsS + rho * 32 + ((q ^ ((rho >> 1) & 3)) * 8));
            aw[mt] = *(const short8*)(AnS + rho * LDA + k0 + q * 8);
        }
#pragma unroll
        for (int nt = 0; nt < NT; ++nt) {
            int rb = wid * (NT * 16) + nt * 16 + mr;
            int ob = rb * 32 + ((q ^ ((rb >> 1) & 3)) * 8);
            short8 bs = *(const short8*)(Bss + ob);
            short8 bn = *(const short8*)(Bsn + ob);
#pragma unroll
            for (int mt = 0; mt < 4; ++mt) {
                acc[mt][nt] = __builtin_amdgcn_mfma_f32_16x16x32_bf16(
                    av[mt], bs, acc[mt][nt], 0, 0, 0);
                acc[mt][nt] = __builtin_amdgcn_mfma_f32_16x16x32_bf16(
                    aw[mt], bn, acc[mt][nt], 0, 0, 0);
            }
        }
        __syncthreads();
    }

    // ---- Epilogue: C/D layout col = lane&15, row = q*4 + reg ----
#pragma unroll
    for (int mt = 0; mt < 4; ++mt) {
#pragma unroll
        for (int i = 0; i < 4; ++i) {
            int row = row0 + mt * 16 + q * 4 + i;
            if (row >= M) continue;
#pragma unroll
            for (int nt = 0; nt < NT; ++nt) {
                int col = wid * (NT * 16) + nt * 16 + mr;
                float v = acc[mt][nt][i] + bias[col];
                if (RELU) v = fmaxf(v, 0.0f);
                if (OUTBF) ((ushort*)Cv)[(size_t)row * N + col] = f2bf(v);
                else       ((float*)Cv)[(size_t)row * N + col] = v;
            }
        }
    }
}

extern "C" void kernel_launch(void* const* d_in, const int* in_sizes, int n_in,
                              void* d_out, int out_size, void* d_ws, size_t ws_size,
                              hipStream_t stream) {
    const float* x    = (const float*)d_in[0];
    const int* src0   = (const int*)d_in[1];
    const int* dst0   = (const int*)d_in[2];
    const int* src1   = (const int*)d_in[3];
    const int* dst1   = (const int*)d_in[4];
    const int* src2   = (const int*)d_in[5];
    const int* dst2   = (const int*)d_in[6];
    const float* Ws0  = (const float*)d_in[10];
    const float* Wn0  = (const float*)d_in[11];
    const float* b0   = (const float*)d_in[12];
    const float* Ws1  = (const float*)d_in[13];
    const float* Wn1  = (const float*)d_in[14];
    const float* b1   = (const float*)d_in[15];
    const float* Ws2  = (const float*)d_in[16];
    const float* Wn2  = (const float*)d_in[17];
    const float* b2   = (const float*)d_in[18];
    float* out = (float*)d_out;

    int E0 = in_sizes[1];
    int E1 = in_sizes[3];
    int E2 = in_sizes[5];

    // Workspace layout (shorts first, then ints; all 16B aligned)
    ushort* wsu  = (ushort*)d_ws;
    ushort* xb50 = wsu;                               // N1*256 (x[:N1] bf16)
    ushort* h1b  = xb50 + (size_t)N1_DST * DH;        // N1*256
    ushort* h2b  = h1b  + (size_t)N1_DST * DH;        // N2*256
    ushort* Wt   = h2b  + (size_t)N2_DST * DH;        // 294912 shorts (6 weights)
    ushort* Ws0t = Wt;
    ushort* Wn0t = Wt + 65536;
    ushort* Ws1t = Wt + 131072;
    ushort* Wn1t = Wt + 196608;
    ushort* Ws2t = Wt + 262144;
    ushort* Wn2t = Wt + 278528;
    int* cnt     = (int*)(Wt + 294912);               // NTOT_DST
    int* off     = cnt + NTOT_DST;                    // NTOT_DST+1 (+pad)
    int* cursor  = off + NTOT_DST + 4;                // NTOT_DST
    int* eidx    = cursor + NTOT_DST;                 // EMAX_TOT
    int* partial = eidx + EMAX_TOT;                   // 64 block partials

    // --- Dispatch 1: cooperative prep + CSR build ---
    PrepArgs pa;
    pa.x = x;
    pa.W[0] = Ws0; pa.W[1] = Wn0; pa.W[2] = Ws1;
    pa.W[3] = Wn1; pa.W[4] = Ws2; pa.W[5] = Wn2;
    pa.s0 = src0; pa.d0 = dst0; pa.E0 = E0;
    pa.s1 = src1; pa.d1 = dst1; pa.E1 = E1;
    pa.s2 = src2; pa.d2 = dst2; pa.E2 = E2;
    pa.Wt = Wt; pa.xb50 = xb50;
    pa.cnt = cnt; pa.off = off; pa.cursor = cursor;
    pa.eidx = eidx; pa.partial = partial;
    void* kargs[] = { &pa };
    hipLaunchCooperativeKernel((void*)prep_csr_kernel, dim3(256), dim3(256),
                               kargs, 0, stream);

    const int* off0 = off;
    const int* off1 = off + N1_DST;
    const int* off2 = off + N1_DST + N2_DST;

    // --- Dispatch 2: layer 0 (gather from f32 x, self from xb50) -> h1b ---
    fused_layer<4, true, false, true><<<(N1_DST + 63) / 64, 256, 0, stream>>>(
        x, xb50, off0, eidx, Ws0t, Wn0t, b0, h1b, N1_DST, DH);

    // --- Dispatch 3: layer 1 (gather+self from h1b) -> h2b (ReLU) ---
    fused_layer<4, false, true, true><<<(N2_DST + 63) / 64, 256, 0, stream>>>(
        h1b, h1b, off1, eidx, Ws1t, Wn1t, b1, h2b, N2_DST, DH);

    // --- Dispatch 4: layer 2 (gather+self from h2b) -> out (f32) ---
    fused_layer<1, false, false, false><<<(N3_DST + 63) / 64, 256, 0, stream>>>(
        h2b, h2b, off2, eidx, Ws2t, Wn2t, b2, out, N3_DST, DOUT);
}